// Round 1
// baseline (272.943 us; speedup 1.0000x reference)
//
#include <hip/hip_runtime.h>
#include <math.h>

#define N_NODES 10000
#define E_EDGES 320000
#define EA      (E_EDGES + N_NODES)   // 330000 with self-loops
#define IN_DIM  128
#define HID     512                    // heads*dhead = 8*64
#define HEADS   8
#define DHEAD   64
#define OUT_DIM 32
#define NEG     0.2f

__device__ __forceinline__ float leaky(float x){ return x > 0.f ? x : NEG * x; }

// ---------------- CSR build ----------------
__global__ void k_count(const int* __restrict__ eidx, int* __restrict__ counts){
    int e = blockIdx.x * blockDim.x + threadIdx.x;
    if (e >= EA) return;
    int d = (e < E_EDGES) ? eidx[E_EDGES + e] : (e - E_EDGES);
    atomicAdd(&counts[d], 1);
}

__global__ void k_scan(const int* __restrict__ counts, int* __restrict__ rowptr,
                       int* __restrict__ cursor){
    __shared__ int tsum[256];
    int t = threadIdx.x;
    const int CH = (N_NODES + 255) / 256;   // 40
    int base = t * CH;
    int s = 0;
    for (int i = 0; i < CH; i++){ int idx = base + i; if (idx < N_NODES) s += counts[idx]; }
    tsum[t] = s; __syncthreads();
    for (int off = 1; off < 256; off <<= 1){
        int v = (t >= off) ? tsum[t - off] : 0;
        __syncthreads();
        tsum[t] += v;
        __syncthreads();
    }
    int p = (t == 0) ? 0 : tsum[t - 1];
    for (int i = 0; i < CH; i++){
        int idx = base + i;
        if (idx < N_NODES){ rowptr[idx] = p; cursor[idx] = p; p += counts[idx]; }
    }
    if (t == 0) rowptr[N_NODES] = EA;
}

__global__ void k_scatter(const int* __restrict__ eidx, int* __restrict__ cursor,
                          int* __restrict__ eid){
    int e = blockIdx.x * blockDim.x + threadIdx.x;
    if (e >= EA) return;
    int d = (e < E_EDGES) ? eidx[E_EDGES + e] : (e - E_EDGES);
    int pos = atomicAdd(&cursor[d], 1);
    eid[pos] = e;
}

// ---------------- layer 1: h1 = x @ W1, alpha_s/d folded in ----------------
// block: 512 threads, 8 nodes per block. head == wave (64 cols per head).
__launch_bounds__(512)
__global__ void k_gemm1(const float* __restrict__ x, const float* __restrict__ W1,
                        const float* __restrict__ a1s, const float* __restrict__ a1d,
                        float* __restrict__ h1, float* __restrict__ as1,
                        float* __restrict__ ad1){
    __shared__ float4 xs[8 * 32];        // 8 rows x 128 floats
    int t = threadIdx.x;
    int n0 = blockIdx.x * 8;
    if (t < 256) xs[t] = reinterpret_cast<const float4*>(x + (size_t)n0 * IN_DIM)[t];
    __syncthreads();
    int j = t;
    float acc[8];
#pragma unroll
    for (int i = 0; i < 8; i++) acc[i] = 0.f;
    for (int k4 = 0; k4 < 32; k4++){
        int k = k4 * 4;
        float w0 = W1[(k + 0) * HID + j];
        float w1 = W1[(k + 1) * HID + j];
        float w2 = W1[(k + 2) * HID + j];
        float w3 = W1[(k + 3) * HID + j];
#pragma unroll
        for (int i = 0; i < 8; i++){
            float4 xv = xs[i * 32 + k4];
            acc[i] += xv.x * w0 + xv.y * w1 + xv.z * w2 + xv.w * w3;
        }
    }
#pragma unroll
    for (int i = 0; i < 8; i++) h1[(size_t)(n0 + i) * HID + j] = acc[i];
    // alpha reductions: a1s/a1d flat [512]; head h = j>>6 spans exactly one wave
    int lane = t & 63;
    int head = t >> 6;
    float asv = a1s[j];
    float adv = a1d[j];
#pragma unroll
    for (int i = 0; i < 8; i++){
        float vs = acc[i] * asv;
        float vd = acc[i] * adv;
#pragma unroll
        for (int off = 32; off >= 1; off >>= 1){
            vs += __shfl_down(vs, off);
            vd += __shfl_down(vd, off);
        }
        if (lane == 0){
            as1[(n0 + i) * HEADS + head] = vs;
            ad1[(n0 + i) * HEADS + head] = vd;
        }
    }
}

// ---------------- layer 1: fused segment softmax + aggregate + bias + ELU --------
// one block (256 threads) per destination node; thread t owns dims t and t+256.
__launch_bounds__(256)
__global__ void k_agg1(const float* __restrict__ h1, const float* __restrict__ as1,
                       const float* __restrict__ ad1, const int* __restrict__ rowptr,
                       const int* __restrict__ eid, const int* __restrict__ eidx,
                       const float* __restrict__ b1, float* __restrict__ h1b){
    int n = blockIdx.x;
    int beg = rowptr[n], end = rowptr[n + 1];
    int cnt = end - beg;
    int t = threadIdx.x;
    __shared__ int   s_src[1024];
    __shared__ float s_adn[HEADS];
    __shared__ float s_red[4][HEADS];
    __shared__ float s_m[HEADS];
    if (t < HEADS) s_adn[t] = ad1[n * HEADS + t];
    __syncthreads();
    // pass 1: per-head max over edges (parallel over edges)
    float pm[HEADS];
#pragma unroll
    for (int h = 0; h < HEADS; h++) pm[h] = -INFINITY;
    for (int i = t; i < cnt; i += 256){
        int e = eid[beg + i];
        int s = (e < E_EDGES) ? eidx[e] : (e - E_EDGES);
        if (i < 1024) s_src[i] = s;
#pragma unroll
        for (int h = 0; h < HEADS; h++)
            pm[h] = fmaxf(pm[h], leaky(as1[s * HEADS + h] + s_adn[h]));
    }
#pragma unroll
    for (int h = 0; h < HEADS; h++)
#pragma unroll
        for (int off = 32; off >= 1; off >>= 1)
            pm[h] = fmaxf(pm[h], __shfl_down(pm[h], off));
    int wv = t >> 6;
    if ((t & 63) == 0)
#pragma unroll
        for (int h = 0; h < HEADS; h++) s_red[wv][h] = pm[h];
    __syncthreads();
    if (t < HEADS)
        s_m[t] = fmaxf(fmaxf(s_red[0][t], s_red[1][t]), fmaxf(s_red[2][t], s_red[3][t]));
    __syncthreads();
    // pass 2: accumulate exp(logit-m)*h1[src]; denominator is redundant per thread
    int d_lo = t, d_hi = t + 256;
    int h_lo = t >> 6, h_hi = h_lo + 4;
    float m_lo = s_m[h_lo], m_hi = s_m[h_hi];
    float adlo = s_adn[h_lo], adhi = s_adn[h_hi];
    float acc_lo = 0.f, acc_hi = 0.f, den_lo = 0.f, den_hi = 0.f;
    for (int i = 0; i < cnt; i++){
        int s;
        if (i < 1024) s = s_src[i];
        else { int e = eid[beg + i]; s = (e < E_EDGES) ? eidx[e] : (e - E_EDGES); }
        float w_lo = __expf(leaky(as1[s * HEADS + h_lo] + adlo) - m_lo);
        float w_hi = __expf(leaky(as1[s * HEADS + h_hi] + adhi) - m_hi);
        acc_lo += w_lo * h1[(size_t)s * HID + d_lo];
        acc_hi += w_hi * h1[(size_t)s * HID + d_hi];
        den_lo += w_lo; den_hi += w_hi;
    }
    float o_lo = acc_lo / den_lo + b1[d_lo];
    float o_hi = acc_hi / den_hi + b1[d_hi];
    h1b[(size_t)n * HID + d_lo] = o_lo > 0.f ? o_lo : expm1f(o_lo);
    h1b[(size_t)n * HID + d_hi] = o_hi > 0.f ? o_hi : expm1f(o_hi);
}

// ---------------- layer 2: h2 = h1b @ W2, alpha2 folded in ----------------
// block 512 = 16 nodes x 32 cols
__launch_bounds__(512)
__global__ void k_gemm2(const float* __restrict__ h1b, const float* __restrict__ W2,
                        const float* __restrict__ a2s, const float* __restrict__ a2d,
                        float* __restrict__ h2, float* __restrict__ as2,
                        float* __restrict__ ad2){
    __shared__ float4 hs[16 * 128];      // 16 rows x 512 floats = 32 KiB
    int t = threadIdx.x;
    int n0 = blockIdx.x * 16;
    const float4* src = reinterpret_cast<const float4*>(h1b + (size_t)n0 * HID);
    for (int i = t; i < 2048; i += 512) hs[i] = src[i];
    __syncthreads();
    int nl = t >> 5, c = t & 31;
    float acc = 0.f;
    for (int k4 = 0; k4 < 128; k4++){
        float4 hv = hs[nl * 128 + k4];
        acc += hv.x * W2[(k4 * 4 + 0) * OUT_DIM + c];
        acc += hv.y * W2[(k4 * 4 + 1) * OUT_DIM + c];
        acc += hv.z * W2[(k4 * 4 + 2) * OUT_DIM + c];
        acc += hv.w * W2[(k4 * 4 + 3) * OUT_DIM + c];
    }
    h2[(size_t)(n0 + nl) * OUT_DIM + c] = acc;
    float vs = acc * a2s[c];
    float vd = acc * a2d[c];
#pragma unroll
    for (int off = 16; off >= 1; off >>= 1){
        vs += __shfl_xor(vs, off);
        vd += __shfl_xor(vd, off);
    }
    if (c == 0){ as2[n0 + nl] = vs; ad2[n0 + nl] = vd; }
}

// ---------------- layer 2: fused softmax + aggregate + bias ----------------
// one wave (64 threads) per destination node; lanes 0..31 own output dims.
__launch_bounds__(64)
__global__ void k_agg2(const float* __restrict__ h2, const float* __restrict__ as2,
                       const float* __restrict__ ad2, const int* __restrict__ rowptr,
                       const int* __restrict__ eid, const int* __restrict__ eidx,
                       const float* __restrict__ b2, float* __restrict__ out){
    int n = blockIdx.x;
    int beg = rowptr[n], end = rowptr[n + 1];
    int cnt = end - beg;
    int t = threadIdx.x;
    __shared__ int s_src[1024];
    float adn = ad2[n];
    float pm = -INFINITY;
    for (int i = t; i < cnt; i += 64){
        int e = eid[beg + i];
        int s = (e < E_EDGES) ? eidx[e] : (e - E_EDGES);
        if (i < 1024) s_src[i] = s;
        pm = fmaxf(pm, leaky(as2[s] + adn));
    }
#pragma unroll
    for (int off = 32; off >= 1; off >>= 1)
        pm = fmaxf(pm, __shfl_xor(pm, off));
    __syncthreads();
    float acc = 0.f, den = 0.f;
    for (int i = 0; i < cnt; i++){
        int s;
        if (i < 1024) s = s_src[i];
        else { int e = eid[beg + i]; s = (e < E_EDGES) ? eidx[e] : (e - E_EDGES); }
        float w = __expf(leaky(as2[s] + adn) - pm);
        den += w;
        if (t < OUT_DIM) acc += w * h2[(size_t)s * OUT_DIM + t];
    }
    if (t < OUT_DIM) out[(size_t)n * OUT_DIM + t] = acc / den + b2[t];
}

// ---------------- launch ----------------
extern "C" void kernel_launch(void* const* d_in, const int* in_sizes, int n_in,
                              void* d_out, int out_size, void* d_ws, size_t ws_size,
                              hipStream_t stream){
    const float* x   = (const float*)d_in[0];
    const int*  eidx = (const int*)  d_in[1];
    const float* W1  = (const float*)d_in[2];
    const float* a1s = (const float*)d_in[3];
    const float* a1d = (const float*)d_in[4];
    const float* b1  = (const float*)d_in[5];
    const float* W2  = (const float*)d_in[6];
    const float* a2s = (const float*)d_in[7];
    const float* a2d = (const float*)d_in[8];
    const float* b2  = (const float*)d_in[9];
    float* out = (float*)d_out;

    char* ws = (char*)d_ws;
    size_t off = 0;
    auto alloc = [&](size_t bytes) -> void* {
        void* p = ws + off;
        off += (bytes + 255) & ~(size_t)255;
        return p;
    };
    float* h1   = (float*)alloc((size_t)N_NODES * HID * 4);
    float* h1b  = (float*)alloc((size_t)N_NODES * HID * 4);
    float* as1  = (float*)alloc((size_t)N_NODES * HEADS * 4);
    float* ad1  = (float*)alloc((size_t)N_NODES * HEADS * 4);
    float* h2   = (float*)alloc((size_t)N_NODES * OUT_DIM * 4);
    float* vs2  = (float*)alloc((size_t)N_NODES * 4);
    float* vd2  = (float*)alloc((size_t)N_NODES * 4);
    int* rowptr = (int*)alloc((size_t)(N_NODES + 1) * 4);
    int* counts = (int*)alloc((size_t)N_NODES * 4);
    int* cursor = (int*)alloc((size_t)N_NODES * 4);
    int* eid    = (int*)alloc((size_t)EA * 4);

    hipMemsetAsync(counts, 0, (size_t)N_NODES * 4, stream);
    k_count  <<<(EA + 255) / 256, 256, 0, stream>>>(eidx, counts);
    k_scan   <<<1, 256, 0, stream>>>(counts, rowptr, cursor);
    k_scatter<<<(EA + 255) / 256, 256, 0, stream>>>(eidx, cursor, eid);

    k_gemm1<<<N_NODES / 8, 512, 0, stream>>>(x, W1, a1s, a1d, h1, as1, ad1);
    k_agg1 <<<N_NODES, 256, 0, stream>>>(h1, as1, ad1, rowptr, eid, eidx, b1, h1b);
    k_gemm2<<<N_NODES / 16, 512, 0, stream>>>(h1b, W2, a2s, a2d, h2, vs2, vd2);
    k_agg2 <<<N_NODES, 64, 0, stream>>>(h2, vs2, vd2, rowptr, eid, eidx, b2, out);
}

// Round 2
// 255.695 us; speedup vs baseline: 1.0675x; 1.0675x over previous
//
#include <hip/hip_runtime.h>
#include <math.h>

#define N_NODES 10000
#define E_EDGES 320000
#define EA      (E_EDGES + N_NODES)   // 330000 with self-loops
#define IN_DIM  128
#define HID     512                    // heads*dhead = 8*64
#define HEADS   8
#define DHEAD   64
#define OUT_DIM 32
#define NEG     0.2f
#define WCAP    256                    // per-node cached-edge capacity (max degree ~60)

__device__ __forceinline__ float leaky(float x){ return x > 0.f ? x : NEG * x; }

// ---------------- CSR build ----------------
__global__ void k_count(const int* __restrict__ eidx, int* __restrict__ counts){
    int e = blockIdx.x * blockDim.x + threadIdx.x;
    if (e >= EA) return;
    int d = (e < E_EDGES) ? eidx[E_EDGES + e] : (e - E_EDGES);
    atomicAdd(&counts[d], 1);
}

__global__ void k_scan(const int* __restrict__ counts, int* __restrict__ rowptr,
                       int* __restrict__ cursor){
    __shared__ int tsum[256];
    int t = threadIdx.x;
    const int CH = (N_NODES + 255) / 256;   // 40
    int base = t * CH;
    int s = 0;
    for (int i = 0; i < CH; i++){ int idx = base + i; if (idx < N_NODES) s += counts[idx]; }
    tsum[t] = s; __syncthreads();
    for (int off = 1; off < 256; off <<= 1){
        int v = (t >= off) ? tsum[t - off] : 0;
        __syncthreads();
        tsum[t] += v;
        __syncthreads();
    }
    int p = (t == 0) ? 0 : tsum[t - 1];
    for (int i = 0; i < CH; i++){
        int idx = base + i;
        if (idx < N_NODES){ rowptr[idx] = p; cursor[idx] = p; p += counts[idx]; }
    }
    if (t == 0) rowptr[N_NODES] = EA;
}

__global__ void k_scatter(const int* __restrict__ eidx, int* __restrict__ cursor,
                          int* __restrict__ eid){
    int e = blockIdx.x * blockDim.x + threadIdx.x;
    if (e >= EA) return;
    int d = (e < E_EDGES) ? eidx[E_EDGES + e] : (e - E_EDGES);
    int pos = atomicAdd(&cursor[d], 1);
    eid[pos] = e;
}

// ---------------- layer 1: h1 = x @ W1, alpha_s/d folded in ----------------
__launch_bounds__(512)
__global__ void k_gemm1(const float* __restrict__ x, const float* __restrict__ W1,
                        const float* __restrict__ a1s, const float* __restrict__ a1d,
                        float* __restrict__ h1, float* __restrict__ as1,
                        float* __restrict__ ad1){
    __shared__ float4 xs[8 * 32];        // 8 rows x 128 floats
    int t = threadIdx.x;
    int n0 = blockIdx.x * 8;
    if (t < 256) xs[t] = reinterpret_cast<const float4*>(x + (size_t)n0 * IN_DIM)[t];
    __syncthreads();
    int j = t;
    float acc[8];
#pragma unroll
    for (int i = 0; i < 8; i++) acc[i] = 0.f;
    for (int k4 = 0; k4 < 32; k4++){
        int k = k4 * 4;
        float w0 = W1[(k + 0) * HID + j];
        float w1 = W1[(k + 1) * HID + j];
        float w2 = W1[(k + 2) * HID + j];
        float w3 = W1[(k + 3) * HID + j];
#pragma unroll
        for (int i = 0; i < 8; i++){
            float4 xv = xs[i * 32 + k4];
            acc[i] += xv.x * w0 + xv.y * w1 + xv.z * w2 + xv.w * w3;
        }
    }
#pragma unroll
    for (int i = 0; i < 8; i++) h1[(size_t)(n0 + i) * HID + j] = acc[i];
    int lane = t & 63;
    int head = t >> 6;
    float asv = a1s[j];
    float adv = a1d[j];
#pragma unroll
    for (int i = 0; i < 8; i++){
        float vs = acc[i] * asv;
        float vd = acc[i] * adv;
#pragma unroll
        for (int off = 32; off >= 1; off >>= 1){
            vs += __shfl_down(vs, off);
            vd += __shfl_down(vd, off);
        }
        if (lane == 0){
            as1[(n0 + i) * HEADS + head] = vs;
            ad1[(n0 + i) * HEADS + head] = vd;
        }
    }
}

// ---------------- layer 1: fused segment softmax + aggregate + bias + ELU --------
// one block (256 threads) per dst node; thread t owns dims 2t, 2t+1 (one head each).
__launch_bounds__(256)
__global__ void k_agg1(const float* __restrict__ h1, const float* __restrict__ as1,
                       const float* __restrict__ ad1, const int* __restrict__ rowptr,
                       const int* __restrict__ eid, const int* __restrict__ eidx,
                       const float* __restrict__ b1, float* __restrict__ h1b){
    int n = blockIdx.x;
    int beg = rowptr[n], end = rowptr[n + 1];
    int cnt = end - beg;
    int t = threadIdx.x;
    __shared__ int   s_src[WCAP];
    __shared__ float s_w[HEADS][WCAP];
    __shared__ float s_adn[HEADS];
    __shared__ float s_red[4][HEADS];
    __shared__ float s_m[HEADS];
    if (t < HEADS) s_adn[t] = ad1[n * HEADS + t];
    __syncthreads();
    // pass 1: compute logits into LDS (once per edge per head), track per-head max
    float pm[HEADS];
#pragma unroll
    for (int h = 0; h < HEADS; h++) pm[h] = -INFINITY;
    for (int i = t; i < cnt; i += 256){
        int e = eid[beg + i];
        int s = (e < E_EDGES) ? eidx[e] : (e - E_EDGES);
        float4 alo = *reinterpret_cast<const float4*>(as1 + (size_t)s * HEADS);
        float4 ahi = *reinterpret_cast<const float4*>(as1 + (size_t)s * HEADS + 4);
        float lg[HEADS];
        lg[0] = leaky(alo.x + s_adn[0]); lg[1] = leaky(alo.y + s_adn[1]);
        lg[2] = leaky(alo.z + s_adn[2]); lg[3] = leaky(alo.w + s_adn[3]);
        lg[4] = leaky(ahi.x + s_adn[4]); lg[5] = leaky(ahi.y + s_adn[5]);
        lg[6] = leaky(ahi.z + s_adn[6]); lg[7] = leaky(ahi.w + s_adn[7]);
        if (i < WCAP){
            s_src[i] = s;
#pragma unroll
            for (int h = 0; h < HEADS; h++) s_w[h][i] = lg[h];
        }
#pragma unroll
        for (int h = 0; h < HEADS; h++) pm[h] = fmaxf(pm[h], lg[h]);
    }
#pragma unroll
    for (int h = 0; h < HEADS; h++)
#pragma unroll
        for (int off = 32; off >= 1; off >>= 1)
            pm[h] = fmaxf(pm[h], __shfl_down(pm[h], off));
    int wv = t >> 6;
    if ((t & 63) == 0)
#pragma unroll
        for (int h = 0; h < HEADS; h++) s_red[wv][h] = pm[h];
    __syncthreads();
    if (t < HEADS)
        s_m[t] = fmaxf(fmaxf(s_red[0][t], s_red[1][t]), fmaxf(s_red[2][t], s_red[3][t]));
    __syncthreads();
    // phase A: exp in place (each edge's 8 weights computed exactly once)
    if (t < cnt && t < WCAP){
#pragma unroll
        for (int h = 0; h < HEADS; h++) s_w[h][t] = __expf(s_w[h][t] - s_m[h]);
    }
    __syncthreads();
    // phase B: serial accumulate; w comes from LDS (broadcast), h1 via float2
    int d0 = 2 * t;
    int h = d0 >> 6;
    float m = s_m[h], adn = s_adn[h];
    float acc0 = 0.f, acc1 = 0.f, den = 0.f;
#pragma unroll 2
    for (int i = 0; i < cnt; i++){
        float w; int s;
        if (i < WCAP){ w = s_w[h][i]; s = s_src[i]; }
        else {
            int e = eid[beg + i];
            s = (e < E_EDGES) ? eidx[e] : (e - E_EDGES);
            w = __expf(leaky(as1[(size_t)s * HEADS + h] + adn) - m);
        }
        float2 hv = *reinterpret_cast<const float2*>(h1 + (size_t)s * HID + d0);
        acc0 += w * hv.x; acc1 += w * hv.y; den += w;
    }
    float o0 = acc0 / den + b1[d0];
    float o1 = acc1 / den + b1[d0 + 1];
    float2 o;
    o.x = o0 > 0.f ? o0 : expm1f(o0);
    o.y = o1 > 0.f ? o1 : expm1f(o1);
    *reinterpret_cast<float2*>(h1b + (size_t)n * HID + d0) = o;
}

// ---------------- layer 2: h2 = h1b @ W2, alpha2 folded in ----------------
__launch_bounds__(512)
__global__ void k_gemm2(const float* __restrict__ h1b, const float* __restrict__ W2,
                        const float* __restrict__ a2s, const float* __restrict__ a2d,
                        float* __restrict__ h2, float* __restrict__ as2,
                        float* __restrict__ ad2){
    __shared__ float4 hs[16 * 128];      // 16 rows x 512 floats = 32 KiB
    int t = threadIdx.x;
    int n0 = blockIdx.x * 16;
    const float4* src = reinterpret_cast<const float4*>(h1b + (size_t)n0 * HID);
    for (int i = t; i < 2048; i += 512) hs[i] = src[i];
    __syncthreads();
    int nl = t >> 5, c = t & 31;
    float acc = 0.f;
    for (int k4 = 0; k4 < 128; k4++){
        float4 hv = hs[nl * 128 + k4];
        acc += hv.x * W2[(k4 * 4 + 0) * OUT_DIM + c];
        acc += hv.y * W2[(k4 * 4 + 1) * OUT_DIM + c];
        acc += hv.z * W2[(k4 * 4 + 2) * OUT_DIM + c];
        acc += hv.w * W2[(k4 * 4 + 3) * OUT_DIM + c];
    }
    h2[(size_t)(n0 + nl) * OUT_DIM + c] = acc;
    float vs = acc * a2s[c];
    float vd = acc * a2d[c];
#pragma unroll
    for (int off = 16; off >= 1; off >>= 1){
        vs += __shfl_xor(vs, off);
        vd += __shfl_xor(vd, off);
    }
    if (c == 0){ as2[n0 + nl] = vs; ad2[n0 + nl] = vd; }
}

// ---------------- layer 2: fused softmax + aggregate + bias ----------------
// 4 nodes per block (one wave each); lane t&31 owns a dim, two wave-halves split edges.
__launch_bounds__(256)
__global__ void k_agg2(const float* __restrict__ h2, const float* __restrict__ as2,
                       const float* __restrict__ ad2, const int* __restrict__ rowptr,
                       const int* __restrict__ eid, const int* __restrict__ eidx,
                       const float* __restrict__ b2, float* __restrict__ out){
    int wv = threadIdx.x >> 6;
    int lane = threadIdx.x & 63;
    int n = blockIdx.x * 4 + wv;
    __shared__ float s_w[4][WCAP];
    __shared__ int   s_src[4][WCAP];
    int beg = rowptr[n], end = rowptr[n + 1];
    int cnt = end - beg;
    float adn = ad2[n];
    float pm = -INFINITY;
    for (int i = lane; i < cnt; i += 64){
        int e = eid[beg + i];
        int s = (e < E_EDGES) ? eidx[e] : (e - E_EDGES);
        float lg = leaky(as2[s] + adn);
        if (i < WCAP){ s_src[wv][i] = s; s_w[wv][i] = lg; }
        pm = fmaxf(pm, lg);
    }
#pragma unroll
    for (int off = 32; off >= 1; off >>= 1)
        pm = fmaxf(pm, __shfl_xor(pm, off));
    __syncthreads();
    if (lane < cnt && lane < WCAP) s_w[wv][lane] = __expf(s_w[wv][lane] - pm);
    __syncthreads();
    int d = lane & 31, half = lane >> 5;
    float acc = 0.f, den = 0.f;
    for (int i = half; i < cnt; i += 2){
        float w; int s;
        if (i < WCAP){ w = s_w[wv][i]; s = s_src[wv][i]; }
        else {
            int e = eid[beg + i];
            s = (e < E_EDGES) ? eidx[e] : (e - E_EDGES);
            w = __expf(leaky(as2[s] + adn) - pm);
        }
        acc += w * h2[(size_t)s * OUT_DIM + d];
        den += w;
    }
    acc += __shfl_xor(acc, 32);
    den += __shfl_xor(den, 32);
    if (lane < OUT_DIM) out[(size_t)n * OUT_DIM + d] = acc / den + b2[d];
}

// ---------------- launch ----------------
extern "C" void kernel_launch(void* const* d_in, const int* in_sizes, int n_in,
                              void* d_out, int out_size, void* d_ws, size_t ws_size,
                              hipStream_t stream){
    const float* x   = (const float*)d_in[0];
    const int*  eidx = (const int*)  d_in[1];
    const float* W1  = (const float*)d_in[2];
    const float* a1s = (const float*)d_in[3];
    const float* a1d = (const float*)d_in[4];
    const float* b1  = (const float*)d_in[5];
    const float* W2  = (const float*)d_in[6];
    const float* a2s = (const float*)d_in[7];
    const float* a2d = (const float*)d_in[8];
    const float* b2  = (const float*)d_in[9];
    float* out = (float*)d_out;

    char* ws = (char*)d_ws;
    size_t off = 0;
    auto alloc = [&](size_t bytes) -> void* {
        void* p = ws + off;
        off += (bytes + 255) & ~(size_t)255;
        return p;
    };
    float* h1   = (float*)alloc((size_t)N_NODES * HID * 4);
    float* h1b  = (float*)alloc((size_t)N_NODES * HID * 4);
    float* as1  = (float*)alloc((size_t)N_NODES * HEADS * 4);
    float* ad1  = (float*)alloc((size_t)N_NODES * HEADS * 4);
    float* h2   = (float*)alloc((size_t)N_NODES * OUT_DIM * 4);
    float* vs2  = (float*)alloc((size_t)N_NODES * 4);
    float* vd2  = (float*)alloc((size_t)N_NODES * 4);
    int* rowptr = (int*)alloc((size_t)(N_NODES + 1) * 4);
    int* counts = (int*)alloc((size_t)N_NODES * 4);
    int* cursor = (int*)alloc((size_t)N_NODES * 4);
    int* eid    = (int*)alloc((size_t)EA * 4);

    hipMemsetAsync(counts, 0, (size_t)N_NODES * 4, stream);
    k_count  <<<(EA + 255) / 256, 256, 0, stream>>>(eidx, counts);
    k_scan   <<<1, 256, 0, stream>>>(counts, rowptr, cursor);
    k_scatter<<<(EA + 255) / 256, 256, 0, stream>>>(eidx, cursor, eid);

    k_gemm1<<<N_NODES / 8, 512, 0, stream>>>(x, W1, a1s, a1d, h1, as1, ad1);
    k_agg1 <<<N_NODES, 256, 0, stream>>>(h1, as1, ad1, rowptr, eid, eidx, b1, h1b);
    k_gemm2<<<N_NODES / 16, 512, 0, stream>>>(h1b, W2, a2s, a2d, h2, vs2, vd2);
    k_agg2 <<<N_NODES / 4, 256, 0, stream>>>(h2, vs2, vd2, rowptr, eid, eidx, b2, out);
}

// Round 3
// 214.202 us; speedup vs baseline: 1.2742x; 1.1937x over previous
//
#include <hip/hip_runtime.h>
#include <math.h>

#define N_NODES 10000
#define E_EDGES 320000
#define EA      (E_EDGES + N_NODES)   // 330000 with self-loops
#define IN_DIM  128
#define HID     512                    // heads*dhead = 8*64
#define HEADS   8
#define DHEAD   64
#define OUT_DIM 32
#define NEG     0.2f
#define WCAP    128                    // per-node cached-edge capacity (deg ~Poisson(32)+1)

__device__ __forceinline__ float leaky(float x){ return x > 0.f ? x : NEG * x; }

__device__ __forceinline__ unsigned short bf16rn(float x){
    unsigned int b = __float_as_uint(x);
    b += 0x7fffu + ((b >> 16) & 1u);
    return (unsigned short)(b >> 16);
}

// ---------------- CSR build ----------------
__global__ void k_count(const int* __restrict__ eidx, int* __restrict__ counts){
    int e = blockIdx.x * blockDim.x + threadIdx.x;
    if (e >= EA) return;
    int d = (e < E_EDGES) ? eidx[E_EDGES + e] : (e - E_EDGES);
    atomicAdd(&counts[d], 1);
}

__global__ void k_scan(const int* __restrict__ counts, int* __restrict__ rowptr,
                       int* __restrict__ cursor){
    __shared__ int tsum[256];
    int t = threadIdx.x;
    const int CH = (N_NODES + 255) / 256;   // 40
    int base = t * CH;
    int s = 0;
    for (int i = 0; i < CH; i++){ int idx = base + i; if (idx < N_NODES) s += counts[idx]; }
    tsum[t] = s; __syncthreads();
    for (int off = 1; off < 256; off <<= 1){
        int v = (t >= off) ? tsum[t - off] : 0;
        __syncthreads();
        tsum[t] += v;
        __syncthreads();
    }
    int p = (t == 0) ? 0 : tsum[t - 1];
    for (int i = 0; i < CH; i++){
        int idx = base + i;
        if (idx < N_NODES){ rowptr[idx] = p; cursor[idx] = p; p += counts[idx]; }
    }
    if (t == 0) rowptr[N_NODES] = EA;
}

__global__ void k_scatter(const int* __restrict__ eidx, int* __restrict__ cursor,
                          int* __restrict__ eid){
    int e = blockIdx.x * blockDim.x + threadIdx.x;
    if (e >= EA) return;
    int d = (e < E_EDGES) ? eidx[E_EDGES + e] : (e - E_EDGES);
    int pos = atomicAdd(&cursor[d], 1);
    eid[pos] = e;
}

// ---------------- layer 1: h1 = x @ W1 (bf16 out), alpha_s/d folded in ----------
__launch_bounds__(512)
__global__ void k_gemm1(const float* __restrict__ x, const float* __restrict__ W1,
                        const float* __restrict__ a1s, const float* __restrict__ a1d,
                        unsigned short* __restrict__ h1, float* __restrict__ as1,
                        float* __restrict__ ad1){
    __shared__ float4 xs[8 * 32];        // 8 rows x 128 floats
    int t = threadIdx.x;
    int n0 = blockIdx.x * 8;
    if (t < 256) xs[t] = reinterpret_cast<const float4*>(x + (size_t)n0 * IN_DIM)[t];
    __syncthreads();
    int j = t;
    float acc[8];
#pragma unroll
    for (int i = 0; i < 8; i++) acc[i] = 0.f;
    for (int k4 = 0; k4 < 32; k4++){
        int k = k4 * 4;
        float w0 = W1[(k + 0) * HID + j];
        float w1 = W1[(k + 1) * HID + j];
        float w2 = W1[(k + 2) * HID + j];
        float w3 = W1[(k + 3) * HID + j];
#pragma unroll
        for (int i = 0; i < 8; i++){
            float4 xv = xs[i * 32 + k4];
            acc[i] += xv.x * w0 + xv.y * w1 + xv.z * w2 + xv.w * w3;
        }
    }
#pragma unroll
    for (int i = 0; i < 8; i++) h1[(size_t)(n0 + i) * HID + j] = bf16rn(acc[i]);
    int lane = t & 63;
    int head = t >> 6;
    float asv = a1s[j];
    float adv = a1d[j];
#pragma unroll
    for (int i = 0; i < 8; i++){
        float vs = acc[i] * asv;
        float vd = acc[i] * adv;
#pragma unroll
        for (int off = 32; off >= 1; off >>= 1){
            vs += __shfl_down(vs, off);
            vd += __shfl_down(vd, off);
        }
        if (lane == 0){
            as1[(n0 + i) * HEADS + head] = vs;
            ad1[(n0 + i) * HEADS + head] = vd;
        }
    }
}

// ---------------- layer 1: fused segment softmax + aggregate + bias + ELU --------
// one block (128 threads) per dst node; thread t owns dims 4t..4t+3 (head t>>4).
__launch_bounds__(128)
__global__ void k_agg1(const unsigned short* __restrict__ h1,
                       const float* __restrict__ as1,
                       const float* __restrict__ ad1, const int* __restrict__ rowptr,
                       const int* __restrict__ eid, const int* __restrict__ eidx,
                       const float* __restrict__ b1, float* __restrict__ h1b){
    int n = blockIdx.x;
    int beg = rowptr[n], end = rowptr[n + 1];
    int cnt = end - beg;
    int t = threadIdx.x;
    __shared__ int   s_src[WCAP];
    __shared__ float s_w[HEADS][WCAP];
    __shared__ float s_adn[HEADS];
    __shared__ float s_red[2][HEADS];
    __shared__ float s_m[HEADS];
    if (t < HEADS) s_adn[t] = ad1[n * HEADS + t];
    __syncthreads();
    // pass 1: compute logits into LDS (once per edge per head), track per-head max
    float pm[HEADS];
#pragma unroll
    for (int h = 0; h < HEADS; h++) pm[h] = -INFINITY;
    for (int i = t; i < cnt; i += 128){
        int e = eid[beg + i];
        int s = (e < E_EDGES) ? eidx[e] : (e - E_EDGES);
        float4 alo = *reinterpret_cast<const float4*>(as1 + (size_t)s * HEADS);
        float4 ahi = *reinterpret_cast<const float4*>(as1 + (size_t)s * HEADS + 4);
        float lg[HEADS];
        lg[0] = leaky(alo.x + s_adn[0]); lg[1] = leaky(alo.y + s_adn[1]);
        lg[2] = leaky(alo.z + s_adn[2]); lg[3] = leaky(alo.w + s_adn[3]);
        lg[4] = leaky(ahi.x + s_adn[4]); lg[5] = leaky(ahi.y + s_adn[5]);
        lg[6] = leaky(ahi.z + s_adn[6]); lg[7] = leaky(ahi.w + s_adn[7]);
        if (i < WCAP){
            s_src[i] = s;
#pragma unroll
            for (int h = 0; h < HEADS; h++) s_w[h][i] = lg[h];
        }
#pragma unroll
        for (int h = 0; h < HEADS; h++) pm[h] = fmaxf(pm[h], lg[h]);
    }
#pragma unroll
    for (int h = 0; h < HEADS; h++)
#pragma unroll
        for (int off = 32; off >= 1; off >>= 1)
            pm[h] = fmaxf(pm[h], __shfl_down(pm[h], off));
    int wv = t >> 6;
    if ((t & 63) == 0)
#pragma unroll
        for (int h = 0; h < HEADS; h++) s_red[wv][h] = pm[h];
    __syncthreads();
    if (t < HEADS) s_m[t] = fmaxf(s_red[0][t], s_red[1][t]);
    __syncthreads();
    // phase A: exp in place (each edge's 8 weights computed exactly once)
    if (t < cnt && t < WCAP){
#pragma unroll
        for (int h = 0; h < HEADS; h++) s_w[h][t] = __expf(s_w[h][t] - s_m[h]);
    }
    __syncthreads();
    // phase B: serial accumulate; w from LDS broadcast, h1 via uint2 (4 bf16)
    int d0 = 4 * t;
    int h = t >> 4;
    float m = s_m[h], adn = s_adn[h];
    float acc0 = 0.f, acc1 = 0.f, acc2 = 0.f, acc3 = 0.f, den = 0.f;
#pragma unroll 2
    for (int i = 0; i < cnt; i++){
        float w; int s;
        if (i < WCAP){ w = s_w[h][i]; s = s_src[i]; }
        else {
            int e = eid[beg + i];
            s = (e < E_EDGES) ? eidx[e] : (e - E_EDGES);
            w = __expf(leaky(as1[(size_t)s * HEADS + h] + adn) - m);
        }
        uint2 hv = *reinterpret_cast<const uint2*>(h1 + (size_t)s * HID + d0);
        float f0 = __uint_as_float(hv.x << 16);
        float f1 = __uint_as_float(hv.x & 0xffff0000u);
        float f2 = __uint_as_float(hv.y << 16);
        float f3 = __uint_as_float(hv.y & 0xffff0000u);
        acc0 += w * f0; acc1 += w * f1; acc2 += w * f2; acc3 += w * f3;
        den += w;
    }
    float4 bv = *reinterpret_cast<const float4*>(b1 + d0);
    float rd = 1.f / den;
    float o0 = acc0 * rd + bv.x;
    float o1 = acc1 * rd + bv.y;
    float o2 = acc2 * rd + bv.z;
    float o3 = acc3 * rd + bv.w;
    float4 o;
    o.x = o0 > 0.f ? o0 : expm1f(o0);
    o.y = o1 > 0.f ? o1 : expm1f(o1);
    o.z = o2 > 0.f ? o2 : expm1f(o2);
    o.w = o3 > 0.f ? o3 : expm1f(o3);
    *reinterpret_cast<float4*>(h1b + (size_t)n * HID + d0) = o;
}

// ---------------- layer 2: h2 = h1b @ W2, alpha2 folded in ----------------
__launch_bounds__(512)
__global__ void k_gemm2(const float* __restrict__ h1b, const float* __restrict__ W2,
                        const float* __restrict__ a2s, const float* __restrict__ a2d,
                        float* __restrict__ h2, float* __restrict__ as2,
                        float* __restrict__ ad2){
    __shared__ float4 hs[16 * 128];      // 16 rows x 512 floats = 32 KiB
    int t = threadIdx.x;
    int n0 = blockIdx.x * 16;
    const float4* src = reinterpret_cast<const float4*>(h1b + (size_t)n0 * HID);
    for (int i = t; i < 2048; i += 512) hs[i] = src[i];
    __syncthreads();
    int nl = t >> 5, c = t & 31;
    float acc = 0.f;
    for (int k4 = 0; k4 < 128; k4++){
        float4 hv = hs[nl * 128 + k4];
        acc += hv.x * W2[(k4 * 4 + 0) * OUT_DIM + c];
        acc += hv.y * W2[(k4 * 4 + 1) * OUT_DIM + c];
        acc += hv.z * W2[(k4 * 4 + 2) * OUT_DIM + c];
        acc += hv.w * W2[(k4 * 4 + 3) * OUT_DIM + c];
    }
    h2[(size_t)(n0 + nl) * OUT_DIM + c] = acc;
    float vs = acc * a2s[c];
    float vd = acc * a2d[c];
#pragma unroll
    for (int off = 16; off >= 1; off >>= 1){
        vs += __shfl_xor(vs, off);
        vd += __shfl_xor(vd, off);
    }
    if (c == 0){ as2[n0 + nl] = vs; ad2[n0 + nl] = vd; }
}

// ---------------- layer 2: fused softmax + aggregate + bias ----------------
__launch_bounds__(256)
__global__ void k_agg2(const float* __restrict__ h2, const float* __restrict__ as2,
                       const float* __restrict__ ad2, const int* __restrict__ rowptr,
                       const int* __restrict__ eid, const int* __restrict__ eidx,
                       const float* __restrict__ b2, float* __restrict__ out){
    int wv = threadIdx.x >> 6;
    int lane = threadIdx.x & 63;
    int n = blockIdx.x * 4 + wv;
    __shared__ float s_w[4][WCAP];
    __shared__ int   s_src[4][WCAP];
    int beg = rowptr[n], end = rowptr[n + 1];
    int cnt = end - beg;
    float adn = ad2[n];
    float pm = -INFINITY;
    for (int i = lane; i < cnt; i += 64){
        int e = eid[beg + i];
        int s = (e < E_EDGES) ? eidx[e] : (e - E_EDGES);
        float lg = leaky(as2[s] + adn);
        if (i < WCAP){ s_src[wv][i] = s; s_w[wv][i] = lg; }
        pm = fmaxf(pm, lg);
    }
#pragma unroll
    for (int off = 32; off >= 1; off >>= 1)
        pm = fmaxf(pm, __shfl_xor(pm, off));
    __syncthreads();
    if (lane < cnt && lane < WCAP) s_w[wv][lane] = __expf(s_w[wv][lane] - pm);
    __syncthreads();
    int d = lane & 31, half = lane >> 5;
    float acc = 0.f, den = 0.f;
    for (int i = half; i < cnt; i += 2){
        float w; int s;
        if (i < WCAP){ w = s_w[wv][i]; s = s_src[wv][i]; }
        else {
            int e = eid[beg + i];
            s = (e < E_EDGES) ? eidx[e] : (e - E_EDGES);
            w = __expf(leaky(as2[s] + adn) - pm);
        }
        acc += w * h2[(size_t)s * OUT_DIM + d];
        den += w;
    }
    acc += __shfl_xor(acc, 32);
    den += __shfl_xor(den, 32);
    if (lane < OUT_DIM) out[(size_t)n * OUT_DIM + d] = acc / den + b2[d];
}

// ---------------- launch ----------------
extern "C" void kernel_launch(void* const* d_in, const int* in_sizes, int n_in,
                              void* d_out, int out_size, void* d_ws, size_t ws_size,
                              hipStream_t stream){
    const float* x   = (const float*)d_in[0];
    const int*  eidx = (const int*)  d_in[1];
    const float* W1  = (const float*)d_in[2];
    const float* a1s = (const float*)d_in[3];
    const float* a1d = (const float*)d_in[4];
    const float* b1  = (const float*)d_in[5];
    const float* W2  = (const float*)d_in[6];
    const float* a2s = (const float*)d_in[7];
    const float* a2d = (const float*)d_in[8];
    const float* b2  = (const float*)d_in[9];
    float* out = (float*)d_out;

    char* ws = (char*)d_ws;
    size_t off = 0;
    auto alloc = [&](size_t bytes) -> void* {
        void* p = ws + off;
        off += (bytes + 255) & ~(size_t)255;
        return p;
    };
    unsigned short* h1 = (unsigned short*)alloc((size_t)N_NODES * HID * 2);
    float* h1b  = (float*)alloc((size_t)N_NODES * HID * 4);
    float* as1  = (float*)alloc((size_t)N_NODES * HEADS * 4);
    float* ad1  = (float*)alloc((size_t)N_NODES * HEADS * 4);
    float* h2   = (float*)alloc((size_t)N_NODES * OUT_DIM * 4);
    float* vs2  = (float*)alloc((size_t)N_NODES * 4);
    float* vd2  = (float*)alloc((size_t)N_NODES * 4);
    int* rowptr = (int*)alloc((size_t)(N_NODES + 1) * 4);
    int* counts = (int*)alloc((size_t)N_NODES * 4);
    int* cursor = (int*)alloc((size_t)N_NODES * 4);
    int* eid    = (int*)alloc((size_t)EA * 4);

    hipMemsetAsync(counts, 0, (size_t)N_NODES * 4, stream);
    k_count  <<<(EA + 255) / 256, 256, 0, stream>>>(eidx, counts);
    k_scan   <<<1, 256, 0, stream>>>(counts, rowptr, cursor);
    k_scatter<<<(EA + 255) / 256, 256, 0, stream>>>(eidx, cursor, eid);

    k_gemm1<<<N_NODES / 8, 512, 0, stream>>>(x, W1, a1s, a1d, h1, as1, ad1);
    k_agg1 <<<N_NODES, 128, 0, stream>>>(h1, as1, ad1, rowptr, eid, eidx, b1, h1b);
    k_gemm2<<<N_NODES / 16, 512, 0, stream>>>(h1b, W2, a2s, a2d, h2, vs2, vd2);
    k_agg2 <<<N_NODES / 4, 256, 0, stream>>>(h2, vs2, vd2, rowptr, eid, eidx, b2, out);
}